// Round 2
// baseline (174.039 us; speedup 1.0000x reference)
//
#include <hip/hip_runtime.h>
#include <math.h>

// Dims: B=2, H=256, W=256, C=64, heads=8, dh=64, hd=512, dim_out=64.
// Inputs fp32, output fp32 (proven r1/r2). Internals bf16 + MFMA.
//
// attn[b,h,i,j] = (Wk_i^T G[b] Wq_j)/(||k_i|| ||q_j||)*rescale[h],
// G[b] = Xd^T Xd (Gram of 2x2-avg-pooled input).
// out = x@W_eff[b] + bproj + dwconv2(gelu(dwconv1(x@W_pos + bc1d)))
// W_eff[b] = Wv @ blockdiag_h(attn_h^T) @ Wproj,  W_pos = Wv @ Wc1d.
//
// R1: occupancy restructure of k_front/k_mid1 (was 1 blk/CU latency-bound).
// R2: k_gwqk_norms folded into k_mid2's 16 attn blocks (T/nq/nk computed
//     in-block from G4); 4 launches total. Attn-block LDS kept at 53248 B
//     (conv1 stays 3 blocks/CU) via region time-sharing + norm-in-pad-cols.

typedef unsigned short u16;
typedef unsigned int u32;
typedef __attribute__((ext_vector_type(8))) short short8;
typedef __attribute__((ext_vector_type(4))) float f32x4;

__device__ __forceinline__ float bf2f(u16 h) { return __uint_as_float(((u32)h) << 16); }
__device__ __forceinline__ u16 f2bf(float f) {
    u32 u = __float_as_uint(f);
    return (u16)((u + 0x7fffu + ((u >> 16) & 1u)) >> 16);
}
__device__ __forceinline__ float rbf(float f) { return bf2f(f2bf(f)); }
__device__ __forceinline__ u32 pk2(float lo, float hi) {
    return (u32)f2bf(lo) | ((u32)f2bf(hi) << 16);
}
__device__ __forceinline__ void unpack8(uint4 v, float* f) {
    u32 a[4] = {v.x, v.y, v.z, v.w};
#pragma unroll
    for (int i = 0; i < 4; ++i) {
        f[2 * i]     = __uint_as_float(a[i] << 16);
        f[2 * i + 1] = __uint_as_float(a[i] & 0xffff0000u);
    }
}
__device__ __forceinline__ float gelu_exact(float v) {
    return 0.5f * v * (1.f + erff(v * 0.70710678118654752f));
}

// ---------------------------------------------------------------------------
// K1: blocks 0..322 weight fp32->bf16; 323..386 Wpos = Wv@Wc1d (bf16-rounded,
//     k split across 4 waves); 387..898 pool+Gram partials + xb emit
//     (half-row per block: 64 pooled px).
__global__ __launch_bounds__(256) void k_front(
    const float* __restrict__ x,
    const float* __restrict__ wq_f, const float* __restrict__ wk_f,
    const float* __restrict__ wv_f, const float* __restrict__ rs_f,
    const float* __restrict__ wp_f, const float* __restrict__ bp_f,
    const float* __restrict__ wc_f, const float* __restrict__ bc_f,
    const float* __restrict__ p1_f, const float* __restrict__ p2_f,
    u32* __restrict__ wb32, float* __restrict__ Wpos,
    u16* __restrict__ xb, float* __restrict__ partials) {
    __shared__ float xvs[64 * 68];
    int blk = blockIdx.x;
    int t = threadIdx.x;
    if (blk < 323) {
        u32 pid = (u32)blk * 256u + t;
        if (pid < 82564u) {
            const float* src; u32 p;
            if      (pid < 16384u) { src = wq_f; p = pid; }
            else if (pid < 32768u) { src = wk_f; p = pid - 16384u; }
            else if (pid < 49152u) { src = wv_f; p = pid - 32768u; }
            else if (pid < 49156u) { src = rs_f; p = pid - 49152u; }
            else if (pid < 65540u) { src = wp_f; p = pid - 49156u; }
            else if (pid < 65572u) { src = bp_f; p = pid - 65540u; }
            else if (pid < 81956u) { src = wc_f; p = pid - 65572u; }
            else if (pid < 81988u) { src = bc_f; p = pid - 81956u; }
            else if (pid < 82276u) { src = p1_f; p = pid - 81988u; }
            else                   { src = p2_f; p = pid - 82276u; }
            wb32[pid] = (u32)f2bf(src[2 * p]) | ((u32)f2bf(src[2 * p + 1]) << 16);
        }
    } else if (blk < 387) {
        int c = blk - 323;                    // 0..63, one Wv row per block
        int o = t & 63, ch = t >> 6;          // ch = k-chunk (one per wave)
        const float* wvr = wv_f + c * 512 + ch * 128;
        const float* wcr = wc_f + (size_t)(ch * 128) * 64 + o;
        float s = 0.f;
        for (int kk = 0; kk < 128; ++kk)
            s += rbf(wvr[kk]) * rbf(wcr[(size_t)kk * 64]);
        xvs[ch * 64 + o] = s;
        __syncthreads();
        if (t < 64)
            Wpos[c * 64 + t] = (xvs[t] + xvs[64 + t]) + (xvs[128 + t] + xvs[192 + t]);
    } else {
        int gb = blk - 387;                   // 0..511
        int b = gb >> 8, sub = gb & 255;
        int py = sub >> 1, half = sub & 1;
        const size_t rowbase = (size_t)(b * 256 + 2 * py) * 16384 + (size_t)half * 8192;
#pragma unroll
        for (int i2 = 0; i2 < 4; ++i2) {
            int u = t + 256 * i2;
            int P = u >> 4, cq = u & 15;      // P: pooled col within half (0..63)
            size_t o0 = rowbase + (size_t)(2 * P) * 64 + cq * 4;
            float4 a0 = *(const float4*)(x + o0);
            float4 a1 = *(const float4*)(x + o0 + 64);
            float4 a2 = *(const float4*)(x + o0 + 16384);
            float4 a3 = *(const float4*)(x + o0 + 16384 + 64);
            *(uint2*)(xb + o0)              = make_uint2(pk2(a0.x, a0.y), pk2(a0.z, a0.w));
            *(uint2*)(xb + o0 + 64)         = make_uint2(pk2(a1.x, a1.y), pk2(a1.z, a1.w));
            *(uint2*)(xb + o0 + 16384)      = make_uint2(pk2(a2.x, a2.y), pk2(a2.z, a2.w));
            *(uint2*)(xb + o0 + 16384 + 64) = make_uint2(pk2(a3.x, a3.y), pk2(a3.z, a3.w));
            float4 s;
            s.x = 0.25f * (a0.x + a1.x + a2.x + a3.x);
            s.y = 0.25f * (a0.y + a1.y + a2.y + a3.y);
            s.z = 0.25f * (a0.z + a1.z + a2.z + a3.z);
            s.w = 0.25f * (a0.w + a1.w + a2.w + a3.w);
            *(float4*)(&xvs[P * 68 + cq * 4]) = s;
        }
        __syncthreads();
        int r0 = (t >> 4) << 2, c0 = (t & 15) << 2;
        float acc[4][4] = {{0.f}};
        for (int P = 0; P < 64; ++P) {
            float4 av = *(const float4*)(&xvs[P * 68 + r0]);
            float4 bv = *(const float4*)(&xvs[P * 68 + c0]);
            float ar[4] = {av.x, av.y, av.z, av.w};
            float br[4] = {bv.x, bv.y, bv.z, bv.w};
#pragma unroll
            for (int i = 0; i < 4; ++i)
#pragma unroll
                for (int j = 0; j < 4; ++j)
                    acc[i][j] += ar[i] * br[j];
        }
        float* outp = partials + (size_t)gb * 4096;
#pragma unroll
        for (int i = 0; i < 4; ++i)
            *(float4*)(&outp[(r0 + i) * 64 + c0]) =
                make_float4(acc[i][0], acc[i][1], acc[i][2], acc[i][3]);
    }
}

// ---------------------------------------------------------------------------
// K2: blocks 0..127 Gram reduce into 4-chunk G4 (+Weff zero);
//     128..1151 pmain (MFMA matvec, 128 px per block).
__global__ __launch_bounds__(256) void k_mid1(
    const float* __restrict__ partials, float* __restrict__ G4, float* __restrict__ Weff,
    const u16* __restrict__ xb, const float* __restrict__ Wpos,
    const u16* __restrict__ bc1d, u16* __restrict__ pbuf) {
    __shared__ u16 sm[128 * 72];
    int blk = blockIdx.x;
    int t = threadIdx.x;
    if (blk < 128) {
        int gid = blk * 256 + t;              // 0..32767
        int e = gid & 4095, ch = (gid >> 12) & 3, b = gid >> 14;
        const float* p0 = partials + ((size_t)(b * 256 + ch * 64)) * 4096 + e;
        float s = 0.f;
        for (int p = 0; p < 64; ++p)
            s += p0[(size_t)p * 4096];
        G4[gid] = s;
        if (gid < 8192) Weff[gid] = 0.f;
        return;
    }
    int pb = blk - 128;                       // 0..1023
    int lane = t & 63, wv = t >> 6;
    int col = lane & 15, quad = lane >> 4;

    short8 bf[2][4];
#pragma unroll
    for (int kh = 0; kh < 2; ++kh)
#pragma unroll
        for (int nt = 0; nt < 4; ++nt) {
            short8 v;
#pragma unroll
            for (int j = 0; j < 8; ++j)
                v[j] = (short)f2bf(Wpos[(kh * 32 + quad * 8 + j) * 64 + nt * 16 + col]);
            bf[kh][nt] = v;
        }
    float bias[4];
#pragma unroll
    for (int nt = 0; nt < 4; ++nt) bias[nt] = bf2f(bc1d[nt * 16 + col]);

    size_t base = (size_t)pb * 128;
#pragma unroll
    for (int g = 0; g < 2; ++g) {
        int P0 = wv * 32 + g * 16;
        const short8* ap = (const short8*)(xb + (base + P0 + col) * 64);
        short8 a0 = ap[quad];
        short8 a1 = ap[4 + quad];
#pragma unroll
        for (int nt = 0; nt < 4; ++nt) {
            f32x4 acc = {0.f, 0.f, 0.f, 0.f};
            acc = __builtin_amdgcn_mfma_f32_16x16x32_bf16(a0, bf[0][nt], acc, 0, 0, 0);
            acc = __builtin_amdgcn_mfma_f32_16x16x32_bf16(a1, bf[1][nt], acc, 0, 0, 0);
#pragma unroll
            for (int r = 0; r < 4; ++r)
                sm[(P0 + quad * 4 + r) * 72 + nt * 16 + col] = f2bf(acc[r] + bias[nt]);
        }
    }
    __syncthreads();
#pragma unroll
    for (int k = 0; k < 4; ++k) {
        int linear = k * 256 + t;
        int px = linear >> 3, oct = linear & 7;
        uint4 v = *(const uint4*)(&sm[px * 72 + oct * 8]);
        *(uint4*)(pbuf + (base + px) * 64 + oct * 8) = v;
    }
}

// ---------------------------------------------------------------------------
// K3 (was K4): blocks 0..15 self-sufficient attn: G-load -> Tq/Tk -> norms ->
// logits/softmax -> P -> Weff (atomicAdd); blocks 16..1039 conv1.
// Attn LDS layout (53248 B total, matches conv1's 3 blocks/CU budget):
//   [0..17408)      Ts  f32[64*68]: Tq (cols 0..63), nk in col 64, nq in col
//                   65; later reused as Pls.
//   [17408..34816)  Ps  f32[64*68]: norm products; later attns.
//   [34816..53248)  Gs  f32[64*68] (phases 0..B); then Wpjs u16[64*72] @+0
//                   and Wvs u16[64*72] @+9216 (Gs dead).
__global__ __launch_bounds__(256) void k_mid2(
    const u16* __restrict__ wkb, const u16* __restrict__ wqb,
    const u16* __restrict__ wpb, const u16* __restrict__ wvb,
    const u16* __restrict__ rsb,
    const float* __restrict__ G4, float* __restrict__ Weff,
    const u16* __restrict__ pbuf, const u16* __restrict__ wpe1, u16* __restrict__ tbuf) {
    __shared__ __align__(16) char shm[53248];
    int blk = blockIdx.x, t = threadIdx.x;
    if (blk < 16) {
        float* Ts   = (float*)shm;
        float* Ps   = (float*)(shm + 17408);
        float* Gs   = (float*)(shm + 34816);
        u16*   Wpjs = (u16*)(shm + 34816);
        u16*   Wvs  = (u16*)(shm + 34816 + 9216);
        float* attns = Ps;
        float* Pls   = Ts;
        int b = blk >> 3, h = blk & 7;
        int c = t >> 2, jq = t & 3, j0 = jq * 16;
        {   // phase 0: Gs = sum of 4 G4 chunks
            int base = t * 16;
            int row = base >> 6, col = base & 63;
            const float* Gb = G4 + (size_t)b * 16384;
#pragma unroll
            for (int q = 0; q < 4; ++q) {
                float4 g0 = *(const float4*)(&Gb[base + 4 * q]);
                float4 g1 = *(const float4*)(&Gb[4096 + base + 4 * q]);
                float4 g2 = *(const float4*)(&Gb[8192 + base + 4 * q]);
                float4 g3 = *(const float4*)(&Gb[12288 + base + 4 * q]);
                *(float4*)(&Gs[row * 68 + col + 4 * q]) = make_float4(
                    (g0.x + g1.x) + (g2.x + g3.x), (g0.y + g1.y) + (g2.y + g3.y),
                    (g0.z + g1.z) + (g2.z + g3.z), (g0.w + g1.w) + (g2.w + g3.w));
            }
        }
        __syncthreads();
        float Tr[16];
        {   // phase A: Tk = Gs @ Wk_h; Ps = Wk .* Tk (norm products for nk)
#pragma unroll
            for (int jj = 0; jj < 16; ++jj) Tr[jj] = 0.f;
            for (int k = 0; k < 64; ++k) {
                short8 w0 = *(const short8*)(&wkb[k * 512 + h * 64 + j0]);
                short8 w1 = *(const short8*)(&wkb[k * 512 + h * 64 + j0 + 8]);
                float g = Gs[c * 68 + k];
#pragma unroll
                for (int jj = 0; jj < 8; ++jj) {
                    Tr[jj]     += g * bf2f((u16)w0[jj]);
                    Tr[8 + jj] += g * bf2f((u16)w1[jj]);
                }
            }
            short8 wc0 = *(const short8*)(&wkb[c * 512 + h * 64 + j0]);
            short8 wc1 = *(const short8*)(&wkb[c * 512 + h * 64 + j0 + 8]);
#pragma unroll
            for (int jj = 0; jj < 8; ++jj) {
                Ps[c * 68 + j0 + jj]     = bf2f((u16)wc0[jj]) * Tr[jj];
                Ps[c * 68 + j0 + 8 + jj] = bf2f((u16)wc1[jj]) * Tr[8 + jj];
            }
        }
        __syncthreads();
        // phase B: nk reduce (t<64) + Tq = Gs @ Wq_h -> Ts
        if (t < 64) {
            float s = 0.f;
            for (int cc = 0; cc < 64; ++cc) s += Ps[cc * 68 + t];
            Ts[t * 68 + 64] = fmaxf(sqrtf(fmaxf(s, 0.f)), 1e-12f);   // nk
        }
        {
#pragma unroll
            for (int jj = 0; jj < 16; ++jj) Tr[jj] = 0.f;
            for (int k = 0; k < 64; ++k) {
                short8 w0 = *(const short8*)(&wqb[k * 512 + h * 64 + j0]);
                short8 w1 = *(const short8*)(&wqb[k * 512 + h * 64 + j0 + 8]);
                float g = Gs[c * 68 + k];
#pragma unroll
                for (int jj = 0; jj < 8; ++jj) {
                    Tr[jj]     += g * bf2f((u16)w0[jj]);
                    Tr[8 + jj] += g * bf2f((u16)w1[jj]);
                }
            }
#pragma unroll
            for (int q = 0; q < 4; ++q)
                *(float4*)(&Ts[c * 68 + j0 + 4 * q]) =
                    make_float4(Tr[4 * q], Tr[4 * q + 1], Tr[4 * q + 2], Tr[4 * q + 3]);
        }
        __syncthreads();
        {   // phase B2: nq products (Ps free) + Wpjs load (Gs dead)
            short8 wc0 = *(const short8*)(&wqb[c * 512 + h * 64 + j0]);
            short8 wc1 = *(const short8*)(&wqb[c * 512 + h * 64 + j0 + 8]);
#pragma unroll
            for (int jj = 0; jj < 8; ++jj) {
                Ps[c * 68 + j0 + jj]     = bf2f((u16)wc0[jj]) * Tr[jj];
                Ps[c * 68 + j0 + 8 + jj] = bf2f((u16)wc1[jj]) * Tr[8 + jj];
            }
            *(short8*)(&Wpjs[c * 72 + j0])     = *(const short8*)(&wpb[(h * 64 + c) * 64 + j0]);
            *(short8*)(&Wpjs[c * 72 + j0 + 8]) = *(const short8*)(&wpb[(h * 64 + c) * 64 + j0 + 8]);
        }
        __syncthreads();
        // phase B3: nq reduce
        if (t < 64) {
            float s = 0.f;
            for (int cc = 0; cc < 64; ++cc) s += Ps[cc * 68 + t];
            Ts[t * 68 + 65] = fmaxf(sqrtf(fmaxf(s, 0.f)), 1e-12f);   // nq
        }
        __syncthreads();
        {   // phase C: logits + softmax -> attns (Ps region)
            int i = t >> 2;
            float L[16];
#pragma unroll
            for (int jj = 0; jj < 16; ++jj) L[jj] = 0.f;
            for (int c2 = 0; c2 < 64; ++c2) {
                float wk = bf2f(wkb[c2 * 512 + h * 64 + i]);
#pragma unroll
                for (int q = 0; q < 4; ++q) {
                    float4 tv = *(const float4*)(&Ts[c2 * 68 + j0 + 4 * q]);
                    L[4 * q + 0] += wk * tv.x;
                    L[4 * q + 1] += wk * tv.y;
                    L[4 * q + 2] += wk * tv.z;
                    L[4 * q + 3] += wk * tv.w;
                }
            }
            float rs = bf2f(rsb[h]);
            float nki = Ts[i * 68 + 64];
            float nqv[16];
#pragma unroll
            for (int jj = 0; jj < 16; ++jj) nqv[jj] = Ts[(j0 + jj) * 68 + 65];
            float m = -1e30f;
#pragma unroll
            for (int jj = 0; jj < 16; ++jj) {
                L[jj] = L[jj] * rs / (nki * nqv[jj]);
                m = fmaxf(m, L[jj]);
            }
            m = fmaxf(m, __shfl_xor(m, 1));
            m = fmaxf(m, __shfl_xor(m, 2));
            float s = 0.f;
#pragma unroll
            for (int jj = 0; jj < 16; ++jj) {
                L[jj] = __expf(L[jj] - m);
                s += L[jj];
            }
            s += __shfl_xor(s, 1);
            s += __shfl_xor(s, 2);
            float inv = 1.f / s;
#pragma unroll
            for (int q = 0; q < 4; ++q)
                *(float4*)(&attns[i * 68 + j0 + 4 * q]) =
                    make_float4(L[4 * q] * inv, L[4 * q + 1] * inv,
                                L[4 * q + 2] * inv, L[4 * q + 3] * inv);
        }
        __syncthreads();
        {   // phase D: Wvs load + P = attn^T @ Wproj_h -> Pls (Ts region)
            *(short8*)(&Wvs[c * 72 + j0])     = *(const short8*)(&wvb[c * 512 + h * 64 + j0]);
            *(short8*)(&Wvs[c * 72 + j0 + 8]) = *(const short8*)(&wvb[c * 512 + h * 64 + j0 + 8]);
            int j = t >> 2, oq = t & 3;
            float Pl[16];
#pragma unroll
            for (int jj = 0; jj < 16; ++jj) Pl[jj] = 0.f;
            for (int i2 = 0; i2 < 64; ++i2) {
                float a = attns[i2 * 68 + j];
                short8 w0 = *(const short8*)(&Wpjs[i2 * 72 + oq * 16]);
                short8 w1 = *(const short8*)(&Wpjs[i2 * 72 + oq * 16 + 8]);
#pragma unroll
                for (int jj = 0; jj < 8; ++jj) {
                    Pl[jj]     += a * bf2f((u16)w0[jj]);
                    Pl[8 + jj] += a * bf2f((u16)w1[jj]);
                }
            }
#pragma unroll
            for (int q = 0; q < 4; ++q)
                *(float4*)(&Pls[j * 68 + oq * 16 + 4 * q]) =
                    make_float4(Pl[4 * q], Pl[4 * q + 1], Pl[4 * q + 2], Pl[4 * q + 3]);
        }
        __syncthreads();
        {   // phase E: Weff partial: Wv_h @ P -> atomicAdd
            int oq = t & 3;
            float acc[16];
#pragma unroll
            for (int jj = 0; jj < 16; ++jj) acc[jj] = 0.f;
            for (int j2 = 0; j2 < 64; ++j2) {
                float wv = bf2f(Wvs[c * 72 + j2]);
#pragma unroll
                for (int q = 0; q < 4; ++q) {
                    float4 pv = *(const float4*)(&Pls[j2 * 68 + oq * 16 + 4 * q]);
                    acc[4 * q + 0] += wv * pv.x;
                    acc[4 * q + 1] += wv * pv.y;
                    acc[4 * q + 2] += wv * pv.z;
                    acc[4 * q + 3] += wv * pv.w;
                }
            }
            float* W = Weff + b * 4096 + c * 64 + oq * 16;
#pragma unroll
            for (int jj = 0; jj < 16; ++jj) atomicAdd(&W[jj], acc[jj]);
        }
        return;
    }
    // ---- conv1 (proven round-4 body), cb = blk - 16 ----
    u16* sm = (u16*)shm;                       // 204*72 u16 = 29376 B
    int cb = blk - 16;
    int b  = cb >> 9;
    int ty = (cb >> 3) & 63;
    int tx = cb & 7;
    int gy0 = ty * 4, gx0 = tx * 32;

    for (int i = t; i < 1632; i += 256) {
        int px = i >> 3, ch = i & 7;
        int hy = px / 34, hx = px - hy * 34;
        int gy = gy0 + hy - 1, gx = gx0 + hx - 1;
        uint4 v = make_uint4(0, 0, 0, 0);
        if ((unsigned)gy < 256u && (unsigned)gx < 256u)
            v = *(const uint4*)(pbuf + ((size_t)((b << 16) + (gy << 8) + gx)) * 64 + ch * 8);
        *(uint4*)(&sm[px * 72 + ch * 8]) = v;
    }
    int oct = t & 7;
    float w[8][9];
#pragma unroll
    for (int j = 0; j < 8; ++j)
#pragma unroll
        for (int k = 0; k < 9; ++k) w[j][k] = bf2f(wpe1[(oct * 8 + j) * 9 + k]);
    __syncthreads();

#pragma unroll
    for (int s = 0; s < 4; ++s) {
        int lp = (t >> 3) + s * 32;
        int ly = lp >> 5, lx = lp & 31;
        float acc[8] = {0.f, 0.f, 0.f, 0.f, 0.f, 0.f, 0.f, 0.f};
#pragma unroll
        for (int dy = 0; dy < 3; ++dy)
#pragma unroll
            for (int dx = 0; dx < 3; ++dx) {
                int hp = (ly + dy) * 34 + lx + dx;
                uint4 v = *(const uint4*)(&sm[hp * 72 + oct * 8]);
                float f[8];
                unpack8(v, f);
                int tap = dy * 3 + dx;
#pragma unroll
                for (int j = 0; j < 8; ++j) acc[j] += f[j] * w[j][tap];
            }
        u32 pk[4];
#pragma unroll
        for (int q = 0; q < 4; ++q)
            pk[q] = pk2(gelu_exact(acc[2 * q]), gelu_exact(acc[2 * q + 1]));
        size_t gpix = (size_t)(b << 16) + ((size_t)(gy0 + ly) << 8) + gx0 + lx;
        *(uint4*)(tbuf + gpix * 64 + oct * 8) = make_uint4(pk[0], pk[1], pk[2], pk[3]);
    }
}

// ---------------------------------------------------------------------------
// K4: out = xb @ Weff[b] + bproj + dwconv3x3(tbuf, Wpe2) (proven round-4 body)
__global__ __launch_bounds__(256) void k_final(const u16* __restrict__ xb,
                                               const u16* __restrict__ tbuf,
                                               const float* __restrict__ Weff,
                                               const u16* __restrict__ wpe2,
                                               const u16* __restrict__ bproj,
                                               float* __restrict__ out) {
    __shared__ u16 sm[204 * 72];
    __shared__ float stage[128 * 68];
    int t = threadIdx.x;
    int blk = blockIdx.x;
    int b  = blk >> 9;
    int ty = (blk >> 3) & 63;
    int tx = blk & 7;
    int gy0 = ty * 4, gx0 = tx * 32;

    for (int i = t; i < 1632; i += 256) {
        int px = i >> 3, ch = i & 7;
        int hy = px / 34, hx = px - hy * 34;
        int gy = gy0 + hy - 1, gx = gx0 + hx - 1;
        uint4 v = make_uint4(0, 0, 0, 0);
        if ((unsigned)gy < 256u && (unsigned)gx < 256u)
            v = *(const uint4*)(tbuf + ((size_t)((b << 16) + (gy << 8) + gx)) * 64 + ch * 8);
        *(uint4*)(&sm[px * 72 + ch * 8]) = v;
    }
    int oct = t & 7;
    {
        float w[8][9];
#pragma unroll
        for (int j = 0; j < 8; ++j)
#pragma unroll
            for (int k = 0; k < 9; ++k) w[j][k] = bf2f(wpe2[(oct * 8 + j) * 9 + k]);
        __syncthreads();
#pragma unroll
        for (int s = 0; s < 4; ++s) {
            int lp = (t >> 3) + s * 32;
            int ly = lp >> 5, lx = lp & 31;
            float acc[8] = {0.f, 0.f, 0.f, 0.f, 0.f, 0.f, 0.f, 0.f};
#pragma unroll
            for (int dy = 0; dy < 3; ++dy)
#pragma unroll
                for (int dx = 0; dx < 3; ++dx) {
                    int hp = (ly + dy) * 34 + lx + dx;
                    uint4 v = *(const uint4*)(&sm[hp * 72 + oct * 8]);
                    float f[8];
                    unpack8(v, f);
                    int tap = dy * 3 + dx;
#pragma unroll
                    for (int j = 0; j < 8; ++j) acc[j] += f[j] * w[j][tap];
                }
#pragma unroll
            for (int j = 0; j < 8; ++j)
                stage[lp * 68 + oct * 8 + j] = acc[j];
        }
    }
    __syncthreads();

    int lane = t & 63, wv = t >> 6;
    int col = lane & 15, quad = lane >> 4;
    const float* W = Weff + b * 4096;
    short8 bf[2][4];
#pragma unroll
    for (int kh = 0; kh < 2; ++kh)
#pragma unroll
        for (int nt = 0; nt < 4; ++nt) {
            short8 v;
#pragma unroll
            for (int j = 0; j < 8; ++j)
                v[j] = (short)f2bf(W[(kh * 32 + quad * 8 + j) * 64 + nt * 16 + col]);
            bf[kh][nt] = v;
        }
    float bias[4];
#pragma unroll
    for (int nt = 0; nt < 4; ++nt) bias[nt] = bf2f(bproj[nt * 16 + col]);

#pragma unroll
    for (int g = 0; g < 2; ++g) {
        int grp = wv * 2 + g;
        int ly = grp >> 1;
        int lxb = (grp & 1) * 16;
        size_t rowpix = (size_t)(b << 16) + ((size_t)(gy0 + ly) << 8) + gx0;
        const short8* ap = (const short8*)(xb + (rowpix + lxb + col) * 64);
        short8 a0 = ap[quad];
        short8 a1 = ap[4 + quad];
#pragma unroll
        for (int nt = 0; nt < 4; ++nt) {
            f32x4 acc = {0.f, 0.f, 0.f, 0.f};
            acc = __builtin_amdgcn_mfma_f32_16x16x32_bf16(a0, bf[0][nt], acc, 0, 0, 0);
            acc = __builtin_amdgcn_mfma_f32_16x16x32_bf16(a1, bf[1][nt], acc, 0, 0, 0);
#pragma unroll
            for (int r = 0; r < 4; ++r) {
                int lp = ly * 32 + lxb + quad * 4 + r;
                stage[lp * 68 + nt * 16 + col] += acc[r] + bias[nt];
            }
        }
    }
    __syncthreads();

#pragma unroll
    for (int k = 0; k < 8; ++k) {
        int linear = k * 256 + t;
        int px = linear >> 4, c4 = linear & 15;
        int ly = px >> 5, lx = px & 31;
        float4 v = *(const float4*)(&stage[px * 68 + c4 * 4]);
        size_t gpix = (size_t)(b << 16) + ((size_t)(gy0 + ly) << 8) + gx0 + lx;
        *(float4*)(out + gpix * 64 + c4 * 4) = v;
    }
}

// ---------------------------------------------------------------------------
extern "C" void kernel_launch(void* const* d_in, const int* in_sizes, int n_in,
                              void* d_out, int out_size, void* d_ws, size_t ws_size,
                              hipStream_t stream) {
    const float* x = (const float*)d_in[0];
    float* out = (float*)d_out;

    char* w = (char*)d_ws;
    size_t off = 0;
    auto alloc = [&](size_t bytes) -> void* {
        void* p = w + off;
        off += (bytes + 255) & ~(size_t)255;
        return p;
    };
    u16* xb = (u16*)alloc((size_t)16777216 * 2);
    u16* wb = (u16*)alloc((size_t)165128 * 2);
    u16* wqb = wb;
    u16* wkb = wqb + 32768;
    u16* wvb = wkb + 32768;
    u16* rsb = wvb + 32768;
    u16* wpb = rsb + 8;
    u16* bpb = wpb + 32768;
    u16* wcb = bpb + 64;
    u16* bcb = wcb + 32768;
    u16* p1b = bcb + 64;
    u16* p2b = p1b + 576;
    (void)wcb;

    float* partials = (float*)alloc((size_t)512 * 4096 * 4);
    float* G4       = (float*)alloc((size_t)2 * 4 * 4096 * 4);
    float* Weff     = (float*)alloc((size_t)2 * 4096 * 4);
    float* Wpos     = (float*)alloc((size_t)4096 * 4);
    u16*   pbuf     = (u16*)alloc((size_t)2 * 65536 * 64 * 2);
    u16*   tbuf     = (u16*)alloc((size_t)2 * 65536 * 64 * 2);

    hipLaunchKernelGGL(k_front, dim3(899), dim3(256), 0, stream,
                       x,
                       (const float*)d_in[1], (const float*)d_in[2], (const float*)d_in[3],
                       (const float*)d_in[4], (const float*)d_in[5], (const float*)d_in[6],
                       (const float*)d_in[7], (const float*)d_in[8], (const float*)d_in[9],
                       (const float*)d_in[10],
                       (u32*)wb, Wpos, xb, partials);
    hipLaunchKernelGGL(k_mid1, dim3(1152), dim3(256), 0, stream,
                       partials, G4, Weff, xb, Wpos, bcb, pbuf);
    hipLaunchKernelGGL(k_mid2, dim3(1040), dim3(256), 0, stream,
                       wkb, wqb, wpb, wvb, rsb, G4, Weff, pbuf, p1b, tbuf);
    hipLaunchKernelGGL(k_final, dim3(1024), dim3(256), 0, stream,
                       xb, tbuf, Weff, p2b, bpb, out);
}

// Round 3
// 156.500 us; speedup vs baseline: 1.1121x; 1.1121x over previous
//
#include <hip/hip_runtime.h>
#include <math.h>

// Dims: B=2, H=256, W=256, C=64, heads=8, dh=64, hd=512, dim_out=64.
// Inputs fp32, output fp32 (proven r1/r2). Internals bf16 + MFMA.
//
// attn[b,h,i,j] = (Wk_i^T G[b] Wq_j)/(||k_i|| ||q_j||)*rescale[h],
// G[b] = Xd^T Xd (Gram of 2x2-avg-pooled input).
// out = x@W_eff[b] + bproj + dwconv2(gelu(dwconv1(x@W_pos + bc1d)))
// W_eff[b] = Wv @ blockdiag_h(attn_h^T) @ Wproj,  W_pos = Wv @ Wc1d.
//
// R1: occupancy restructure of k_front/k_mid1 (was 1 blk/CU latency-bound).
// R2: k_gwqk_norms folded into k_mid2's 16 attn blocks; 4 launches.
// R3: attn block's five 64x64x64 matvec phases MFMA-ized with split-bf16
//     (hi+lo) operands for fp32-level accuracy; serial t<64 norm reduces
//     -> 4-partial parallel reduce via 1KB scratch. LDS stays 53248 B.

typedef unsigned short u16;
typedef unsigned int u32;
typedef __attribute__((ext_vector_type(8))) short short8;
typedef __attribute__((ext_vector_type(4))) float f32x4;

__device__ __forceinline__ float bf2f(u16 h) { return __uint_as_float(((u32)h) << 16); }
__device__ __forceinline__ u16 f2bf(float f) {
    u32 u = __float_as_uint(f);
    return (u16)((u + 0x7fffu + ((u >> 16) & 1u)) >> 16);
}
__device__ __forceinline__ float rbf(float f) { return bf2f(f2bf(f)); }
__device__ __forceinline__ u32 pk2(float lo, float hi) {
    return (u32)f2bf(lo) | ((u32)f2bf(hi) << 16);
}
__device__ __forceinline__ void unpack8(uint4 v, float* f) {
    u32 a[4] = {v.x, v.y, v.z, v.w};
#pragma unroll
    for (int i = 0; i < 4; ++i) {
        f[2 * i]     = __uint_as_float(a[i] << 16);
        f[2 * i + 1] = __uint_as_float(a[i] & 0xffff0000u);
    }
}
__device__ __forceinline__ float gelu_exact(float v) {
    return 0.5f * v * (1.f + erff(v * 0.70710678118654752f));
}
// split f32 -> bf16 hi + bf16 lo (captures ~16 mantissa bits)
__device__ __forceinline__ void splitbf(float g, short& hi, short& lo) {
    u16 hb = f2bf(g);
    hi = (short)hb;
    lo = (short)f2bf(g - bf2f(hb));
}

// ---------------------------------------------------------------------------
// K1: blocks 0..322 weight fp32->bf16; 323..386 Wpos = Wv@Wc1d (bf16-rounded,
//     k split across 4 waves); 387..898 pool+Gram partials + xb emit
//     (half-row per block: 64 pooled px).
__global__ __launch_bounds__(256) void k_front(
    const float* __restrict__ x,
    const float* __restrict__ wq_f, const float* __restrict__ wk_f,
    const float* __restrict__ wv_f, const float* __restrict__ rs_f,
    const float* __restrict__ wp_f, const float* __restrict__ bp_f,
    const float* __restrict__ wc_f, const float* __restrict__ bc_f,
    const float* __restrict__ p1_f, const float* __restrict__ p2_f,
    u32* __restrict__ wb32, float* __restrict__ Wpos,
    u16* __restrict__ xb, float* __restrict__ partials) {
    __shared__ float xvs[64 * 68];
    int blk = blockIdx.x;
    int t = threadIdx.x;
    if (blk < 323) {
        u32 pid = (u32)blk * 256u + t;
        if (pid < 82564u) {
            const float* src; u32 p;
            if      (pid < 16384u) { src = wq_f; p = pid; }
            else if (pid < 32768u) { src = wk_f; p = pid - 16384u; }
            else if (pid < 49152u) { src = wv_f; p = pid - 32768u; }
            else if (pid < 49156u) { src = rs_f; p = pid - 49152u; }
            else if (pid < 65540u) { src = wp_f; p = pid - 49156u; }
            else if (pid < 65572u) { src = bp_f; p = pid - 65540u; }
            else if (pid < 81956u) { src = wc_f; p = pid - 65572u; }
            else if (pid < 81988u) { src = bc_f; p = pid - 81956u; }
            else if (pid < 82276u) { src = p1_f; p = pid - 81988u; }
            else                   { src = p2_f; p = pid - 82276u; }
            wb32[pid] = (u32)f2bf(src[2 * p]) | ((u32)f2bf(src[2 * p + 1]) << 16);
        }
    } else if (blk < 387) {
        int c = blk - 323;                    // 0..63, one Wv row per block
        int o = t & 63, ch = t >> 6;          // ch = k-chunk (one per wave)
        const float* wvr = wv_f + c * 512 + ch * 128;
        const float* wcr = wc_f + (size_t)(ch * 128) * 64 + o;
        float s = 0.f;
        for (int kk = 0; kk < 128; ++kk)
            s += rbf(wvr[kk]) * rbf(wcr[(size_t)kk * 64]);
        xvs[ch * 64 + o] = s;
        __syncthreads();
        if (t < 64)
            Wpos[c * 64 + t] = (xvs[t] + xvs[64 + t]) + (xvs[128 + t] + xvs[192 + t]);
    } else {
        int gb = blk - 387;                   // 0..511
        int b = gb >> 8, sub = gb & 255;
        int py = sub >> 1, half = sub & 1;
        const size_t rowbase = (size_t)(b * 256 + 2 * py) * 16384 + (size_t)half * 8192;
#pragma unroll
        for (int i2 = 0; i2 < 4; ++i2) {
            int u = t + 256 * i2;
            int P = u >> 4, cq = u & 15;      // P: pooled col within half (0..63)
            size_t o0 = rowbase + (size_t)(2 * P) * 64 + cq * 4;
            float4 a0 = *(const float4*)(x + o0);
            float4 a1 = *(const float4*)(x + o0 + 64);
            float4 a2 = *(const float4*)(x + o0 + 16384);
            float4 a3 = *(const float4*)(x + o0 + 16384 + 64);
            *(uint2*)(xb + o0)              = make_uint2(pk2(a0.x, a0.y), pk2(a0.z, a0.w));
            *(uint2*)(xb + o0 + 64)         = make_uint2(pk2(a1.x, a1.y), pk2(a1.z, a1.w));
            *(uint2*)(xb + o0 + 16384)      = make_uint2(pk2(a2.x, a2.y), pk2(a2.z, a2.w));
            *(uint2*)(xb + o0 + 16384 + 64) = make_uint2(pk2(a3.x, a3.y), pk2(a3.z, a3.w));
            float4 s;
            s.x = 0.25f * (a0.x + a1.x + a2.x + a3.x);
            s.y = 0.25f * (a0.y + a1.y + a2.y + a3.y);
            s.z = 0.25f * (a0.z + a1.z + a2.z + a3.z);
            s.w = 0.25f * (a0.w + a1.w + a2.w + a3.w);
            *(float4*)(&xvs[P * 68 + cq * 4]) = s;
        }
        __syncthreads();
        int r0 = (t >> 4) << 2, c0 = (t & 15) << 2;
        float acc[4][4] = {{0.f}};
        for (int P = 0; P < 64; ++P) {
            float4 av = *(const float4*)(&xvs[P * 68 + r0]);
            float4 bv = *(const float4*)(&xvs[P * 68 + c0]);
            float ar[4] = {av.x, av.y, av.z, av.w};
            float br[4] = {bv.x, bv.y, bv.z, bv.w};
#pragma unroll
            for (int i = 0; i < 4; ++i)
#pragma unroll
                for (int j = 0; j < 4; ++j)
                    acc[i][j] += ar[i] * br[j];
        }
        float* outp = partials + (size_t)gb * 4096;
#pragma unroll
        for (int i = 0; i < 4; ++i)
            *(float4*)(&outp[(r0 + i) * 64 + c0]) =
                make_float4(acc[i][0], acc[i][1], acc[i][2], acc[i][3]);
    }
}

// ---------------------------------------------------------------------------
// K2: blocks 0..127 Gram reduce into 4-chunk G4 (+Weff zero);
//     128..1151 pmain (MFMA matvec, 128 px per block).
__global__ __launch_bounds__(256) void k_mid1(
    const float* __restrict__ partials, float* __restrict__ G4, float* __restrict__ Weff,
    const u16* __restrict__ xb, const float* __restrict__ Wpos,
    const u16* __restrict__ bc1d, u16* __restrict__ pbuf) {
    __shared__ u16 sm[128 * 72];
    int blk = blockIdx.x;
    int t = threadIdx.x;
    if (blk < 128) {
        int gid = blk * 256 + t;              // 0..32767
        int e = gid & 4095, ch = (gid >> 12) & 3, b = gid >> 14;
        const float* p0 = partials + ((size_t)(b * 256 + ch * 64)) * 4096 + e;
        float s = 0.f;
        for (int p = 0; p < 64; ++p)
            s += p0[(size_t)p * 4096];
        G4[gid] = s;
        if (gid < 8192) Weff[gid] = 0.f;
        return;
    }
    int pb = blk - 128;                       // 0..1023
    int lane = t & 63, wv = t >> 6;
    int col = lane & 15, quad = lane >> 4;

    short8 bf[2][4];
#pragma unroll
    for (int kh = 0; kh < 2; ++kh)
#pragma unroll
        for (int nt = 0; nt < 4; ++nt) {
            short8 v;
#pragma unroll
            for (int j = 0; j < 8; ++j)
                v[j] = (short)f2bf(Wpos[(kh * 32 + quad * 8 + j) * 64 + nt * 16 + col]);
            bf[kh][nt] = v;
        }
    float bias[4];
#pragma unroll
    for (int nt = 0; nt < 4; ++nt) bias[nt] = bf2f(bc1d[nt * 16 + col]);

    size_t base = (size_t)pb * 128;
#pragma unroll
    for (int g = 0; g < 2; ++g) {
        int P0 = wv * 32 + g * 16;
        const short8* ap = (const short8*)(xb + (base + P0 + col) * 64);
        short8 a0 = ap[quad];
        short8 a1 = ap[4 + quad];
#pragma unroll
        for (int nt = 0; nt < 4; ++nt) {
            f32x4 acc = {0.f, 0.f, 0.f, 0.f};
            acc = __builtin_amdgcn_mfma_f32_16x16x32_bf16(a0, bf[0][nt], acc, 0, 0, 0);
            acc = __builtin_amdgcn_mfma_f32_16x16x32_bf16(a1, bf[1][nt], acc, 0, 0, 0);
#pragma unroll
            for (int r = 0; r < 4; ++r)
                sm[(P0 + quad * 4 + r) * 72 + nt * 16 + col] = f2bf(acc[r] + bias[nt]);
        }
    }
    __syncthreads();
#pragma unroll
    for (int k = 0; k < 4; ++k) {
        int linear = k * 256 + t;
        int px = linear >> 3, oct = linear & 7;
        uint4 v = *(const uint4*)(&sm[px * 72 + oct * 8]);
        *(uint4*)(pbuf + (base + px) * 64 + oct * 8) = v;
    }
}

// ---------------------------------------------------------------------------
// K3: blocks 0..15 self-sufficient attn (MFMA phases); 16..1039 conv1.
// Attn LDS layout (53248 B):
//   [0..17408)      Ts f32[64*68]: Tq (cols 0..63), nk col 64, nq col 65;
//                   later P.
//   [17408..34816)  Ps f32[64*68]: Tk; then Lraw/attn.
//   [34816..52224)  Gs f32[64*68]: G (dead after phase 1... kept for A-frags).
//   [52224..53248)  scr f32[4*64]: norm partials.
__global__ __launch_bounds__(256) void k_mid2(
    const u16* __restrict__ wkb, const u16* __restrict__ wqb,
    const u16* __restrict__ wpb, const u16* __restrict__ wvb,
    const u16* __restrict__ rsb,
    const float* __restrict__ G4, float* __restrict__ Weff,
    const u16* __restrict__ pbuf, const u16* __restrict__ wpe1, u16* __restrict__ tbuf) {
    __shared__ __align__(16) char shm[53248];
    int blk = blockIdx.x, t = threadIdx.x;
    if (blk < 16) {
        float* Ts  = (float*)shm;
        float* Ps  = (float*)(shm + 17408);
        float* Gs  = (float*)(shm + 34816);
        float* scr = (float*)(shm + 52224);
        int b = blk >> 3, h = blk & 7;
        int lane = t & 63, w = t >> 6;        // w = wave = m-tile
        int lr = lane & 15, lq = lane >> 4;
        {   // phase 0: Gs = sum of 4 G4 chunks
            int base = t * 16;
            int row = base >> 6, col = base & 63;
            const float* Gb = G4 + (size_t)b * 16384;
#pragma unroll
            for (int q = 0; q < 4; ++q) {
                float4 g0 = *(const float4*)(&Gb[base + 4 * q]);
                float4 g1 = *(const float4*)(&Gb[4096 + base + 4 * q]);
                float4 g2 = *(const float4*)(&Gb[8192 + base + 4 * q]);
                float4 g3 = *(const float4*)(&Gb[12288 + base + 4 * q]);
                *(float4*)(&Gs[row * 68 + col + 4 * q]) = make_float4(
                    (g0.x + g1.x) + (g2.x + g3.x), (g0.y + g1.y) + (g2.y + g3.y),
                    (g0.z + g1.z) + (g2.z + g3.z), (g0.w + g1.w) + (g2.w + g3.w));
            }
        }
        __syncthreads();
        {   // phase 1: Tk = G@Wk -> Ps ; Tq = G@Wq -> Ts (split-MFMA).
            // A-frag via G symmetry: A[m][k] = G[k][m] (bit-symmetric Gram).
            short8 ahi[2], alo[2];
#pragma unroll
            for (int ks = 0; ks < 2; ++ks) {
                short8 hi, lo;
#pragma unroll
                for (int jj = 0; jj < 8; ++jj) {
                    short h16, l16;
                    splitbf(Gs[(ks * 32 + lq * 8 + jj) * 68 + w * 16 + lr], h16, l16);
                    hi[jj] = h16; lo[jj] = l16;
                }
                ahi[ks] = hi; alo[ks] = lo;
            }
#pragma unroll
            for (int sel = 0; sel < 2; ++sel) {
                const u16* W = sel ? wqb : wkb;
                float* out = sel ? Ts : Ps;
#pragma unroll
                for (int nt = 0; nt < 4; ++nt) {
                    f32x4 acc = {0.f, 0.f, 0.f, 0.f};
#pragma unroll
                    for (int ks = 0; ks < 2; ++ks) {
                        short8 bv;
#pragma unroll
                        for (int jj = 0; jj < 8; ++jj)
                            bv[jj] = (short)W[(ks * 32 + lq * 8 + jj) * 512 + h * 64 + nt * 16 + lr];
                        acc = __builtin_amdgcn_mfma_f32_16x16x32_bf16(ahi[ks], bv, acc, 0, 0, 0);
                        acc = __builtin_amdgcn_mfma_f32_16x16x32_bf16(alo[ks], bv, acc, 0, 0, 0);
                    }
#pragma unroll
                    for (int r = 0; r < 4; ++r)
                        out[(w * 16 + lq * 4 + r) * 68 + nt * 16 + lr] = acc[r];
                }
            }
        }
        __syncthreads();
        {   // phase 2a: nk partials (Wk .* Tk, 16-row chunks per wave)
            int ci = t & 63, grp = t >> 6;
            float s = 0.f;
#pragma unroll
            for (int cc = 0; cc < 16; ++cc) {
                int c = grp * 16 + cc;
                s += bf2f(wkb[c * 512 + h * 64 + ci]) * Ps[c * 68 + ci];
            }
            scr[grp * 64 + ci] = s;
        }
        __syncthreads();
        // phase 2b: nk combine + Lraw = Wk^T @ Tq -> Ps (split-MFMA)
        if (t < 64) {
            float s = (scr[t] + scr[64 + t]) + (scr[128 + t] + scr[192 + t]);
            Ts[t * 68 + 64] = fmaxf(sqrtf(fmaxf(s, 0.f)), 1e-12f);   // nk
        }
        {
            short8 ak[2];
#pragma unroll
            for (int ks = 0; ks < 2; ++ks) {
                short8 v;
#pragma unroll
                for (int jj = 0; jj < 8; ++jj)
                    v[jj] = (short)wkb[(ks * 32 + lq * 8 + jj) * 512 + h * 64 + w * 16 + lr];
                ak[ks] = v;
            }
#pragma unroll
            for (int nt = 0; nt < 4; ++nt) {
                f32x4 acc = {0.f, 0.f, 0.f, 0.f};
#pragma unroll
                for (int ks = 0; ks < 2; ++ks) {
                    short8 bhi, blo;
#pragma unroll
                    for (int jj = 0; jj < 8; ++jj) {
                        short h16, l16;
                        splitbf(Ts[(ks * 32 + lq * 8 + jj) * 68 + nt * 16 + lr], h16, l16);
                        bhi[jj] = h16; blo[jj] = l16;
                    }
                    acc = __builtin_amdgcn_mfma_f32_16x16x32_bf16(ak[ks], bhi, acc, 0, 0, 0);
                    acc = __builtin_amdgcn_mfma_f32_16x16x32_bf16(ak[ks], blo, acc, 0, 0, 0);
                }
#pragma unroll
                for (int r = 0; r < 4; ++r)
                    Ps[(w * 16 + lq * 4 + r) * 68 + nt * 16 + lr] = acc[r];
            }
        }
        __syncthreads();
        {   // phase 2c: nq partials (Wq .* Tq)
            int ci = t & 63, grp = t >> 6;
            float s = 0.f;
#pragma unroll
            for (int cc = 0; cc < 16; ++cc) {
                int c = grp * 16 + cc;
                s += bf2f(wqb[c * 512 + h * 64 + ci]) * Ts[c * 68 + ci];
            }
            scr[grp * 64 + ci] = s;
        }
        __syncthreads();
        // phase 2d: nq combine
        if (t < 64) {
            float s = (scr[t] + scr[64 + t]) + (scr[128 + t] + scr[192 + t]);
            Ts[t * 68 + 65] = fmaxf(sqrtf(fmaxf(s, 0.f)), 1e-12f);   // nq
        }
        __syncthreads();
        {   // phase 3: scale + softmax (Lraw in Ps) -> attn in place
            int i = t >> 2, jq = t & 3, j0 = jq * 16;
            float L[16];
#pragma unroll
            for (int q = 0; q < 4; ++q) {
                float4 lv = *(const float4*)(&Ps[i * 68 + j0 + 4 * q]);
                L[4 * q] = lv.x; L[4 * q + 1] = lv.y;
                L[4 * q + 2] = lv.z; L[4 * q + 3] = lv.w;
            }
            float rs = bf2f(rsb[h]);
            float nki = Ts[i * 68 + 64];
            float nqv[16];
#pragma unroll
            for (int jj = 0; jj < 16; ++jj) nqv[jj] = Ts[(j0 + jj) * 68 + 65];
            float m = -1e30f;
#pragma unroll
            for (int jj = 0; jj < 16; ++jj) {
                L[jj] = L[jj] * rs / (nki * nqv[jj]);
                m = fmaxf(m, L[jj]);
            }
            m = fmaxf(m, __shfl_xor(m, 1));
            m = fmaxf(m, __shfl_xor(m, 2));
            float s = 0.f;
#pragma unroll
            for (int jj = 0; jj < 16; ++jj) {
                L[jj] = __expf(L[jj] - m);
                s += L[jj];
            }
            s += __shfl_xor(s, 1);
            s += __shfl_xor(s, 2);
            float inv = 1.f / s;
#pragma unroll
            for (int q = 0; q < 4; ++q)
                *(float4*)(&Ps[i * 68 + j0 + 4 * q]) =
                    make_float4(L[4 * q] * inv, L[4 * q + 1] * inv,
                                L[4 * q + 2] * inv, L[4 * q + 3] * inv);
        }
        __syncthreads();
        {   // phase 4: P = attn^T @ Wproj_h -> Ts (split-MFMA)
            short8 ahi[2], alo[2];
#pragma unroll
            for (int ks = 0; ks < 2; ++ks) {
                short8 hi, lo;
#pragma unroll
                for (int jj = 0; jj < 8; ++jj) {
                    short h16, l16;
                    splitbf(Ps[(ks * 32 + lq * 8 + jj) * 68 + w * 16 + lr], h16, l16);
                    hi[jj] = h16; lo[jj] = l16;
                }
                ahi[ks] = hi; alo[ks] = lo;
            }
#pragma unroll
            for (int nt = 0; nt < 4; ++nt) {
                f32x4 acc = {0.f, 0.f, 0.f, 0.f};
#pragma unroll
                for (int ks = 0; ks < 2; ++ks) {
                    short8 bv;
#pragma unroll
                    for (int jj = 0; jj < 8; ++jj)
                        bv[jj] = (short)wpb[(h * 64 + ks * 32 + lq * 8 + jj) * 64 + nt * 16 + lr];
                    acc = __builtin_amdgcn_mfma_f32_16x16x32_bf16(ahi[ks], bv, acc, 0, 0, 0);
                    acc = __builtin_amdgcn_mfma_f32_16x16x32_bf16(alo[ks], bv, acc, 0, 0, 0);
                }
#pragma unroll
                for (int r = 0; r < 4; ++r)
                    Ts[(w * 16 + lq * 4 + r) * 68 + nt * 16 + lr] = acc[r];
            }
        }
        __syncthreads();
        {   // phase 5: Weff += Wv_h @ P (split-MFMA on P) -> atomicAdd
            short8 av[2];
#pragma unroll
            for (int ks = 0; ks < 2; ++ks)
                av[ks] = *(const short8*)(&wvb[(w * 16 + lr) * 512 + h * 64 + ks * 32 + lq * 8]);
            float* W = Weff + b * 4096;
#pragma unroll
            for (int nt = 0; nt < 4; ++nt) {
                f32x4 acc = {0.f, 0.f, 0.f, 0.f};
#pragma unroll
                for (int ks = 0; ks < 2; ++ks) {
                    short8 bhi, blo;
#pragma unroll
                    for (int jj = 0; jj < 8; ++jj) {
                        short h16, l16;
                        splitbf(Ts[(ks * 32 + lq * 8 + jj) * 68 + nt * 16 + lr], h16, l16);
                        bhi[jj] = h16; blo[jj] = l16;
                    }
                    acc = __builtin_amdgcn_mfma_f32_16x16x32_bf16(av[ks], bhi, acc, 0, 0, 0);
                    acc = __builtin_amdgcn_mfma_f32_16x16x32_bf16(av[ks], blo, acc, 0, 0, 0);
                }
#pragma unroll
                for (int r = 0; r < 4; ++r)
                    atomicAdd(&W[(w * 16 + lq * 4 + r) * 64 + nt * 16 + lr], acc[r]);
            }
        }
        return;
    }
    // ---- conv1 (proven round-4 body), cb = blk - 16 ----
    u16* sm = (u16*)shm;                       // 204*72 u16 = 29376 B
    int cb = blk - 16;
    int b  = cb >> 9;
    int ty = (cb >> 3) & 63;
    int tx = cb & 7;
    int gy0 = ty * 4, gx0 = tx * 32;

    for (int i = t; i < 1632; i += 256) {
        int px = i >> 3, ch = i & 7;
        int hy = px / 34, hx = px - hy * 34;
        int gy = gy0 + hy - 1, gx = gx0 + hx - 1;
        uint4 v = make_uint4(0, 0, 0, 0);
        if ((unsigned)gy < 256u && (unsigned)gx < 256u)
            v = *(const uint4*)(pbuf + ((size_t)((b << 16) + (gy << 8) + gx)) * 64 + ch * 8);
        *(uint4*)(&sm[px * 72 + ch * 8]) = v;
    }
    int oct = t & 7;
    float w[8][9];
#pragma unroll
    for (int j = 0; j < 8; ++j)
#pragma unroll
        for (int k = 0; k < 9; ++k) w[j][k] = bf2f(wpe1[(oct * 8 + j) * 9 + k]);
    __syncthreads();

#pragma unroll
    for (int s = 0; s < 4; ++s) {
        int lp = (t >> 3) + s * 32;
        int ly = lp >> 5, lx = lp & 31;
        float acc[8] = {0.f, 0.f, 0.f, 0.f, 0.f, 0.f, 0.f, 0.f};
#pragma unroll
        for (int dy = 0; dy < 3; ++dy)
#pragma unroll
            for (int dx = 0; dx < 3; ++dx) {
                int hp = (ly + dy) * 34 + lx + dx;
                uint4 v = *(const uint4*)(&sm[hp * 72 + oct * 8]);
                float f[8];
                unpack8(v, f);
                int tap = dy * 3 + dx;
#pragma unroll
                for (int j = 0; j < 8; ++j) acc[j] += f[j] * w[j][tap];
            }
        u32 pk[4];
#pragma unroll
        for (int q = 0; q < 4; ++q)
            pk[q] = pk2(gelu_exact(acc[2 * q]), gelu_exact(acc[2 * q + 1]));
        size_t gpix = (size_t)(b << 16) + ((size_t)(gy0 + ly) << 8) + gx0 + lx;
        *(uint4*)(tbuf + gpix * 64 + oct * 8) = make_uint4(pk[0], pk[1], pk[2], pk[3]);
    }
}

// ---------------------------------------------------------------------------
// K4: out = xb @ Weff[b] + bproj + dwconv3x3(tbuf, Wpe2) (proven round-4 body)
__global__ __launch_bounds__(256) void k_final(const u16* __restrict__ xb,
                                               const u16* __restrict__ tbuf,
                                               const float* __restrict__ Weff,
                                               const u16* __restrict__ wpe2,
                                               const u16* __restrict__ bproj,
                                               float* __restrict__ out) {
    __shared__ u16 sm[204 * 72];
    __shared__ float stage[128 * 68];
    int t = threadIdx.x;
    int blk = blockIdx.x;
    int b  = blk >> 9;
    int ty = (blk >> 3) & 63;
    int tx = blk & 7;
    int gy0 = ty * 4, gx0 = tx * 32;

    for (int i = t; i < 1632; i += 256) {
        int px = i >> 3, ch = i & 7;
        int hy = px / 34, hx = px - hy * 34;
        int gy = gy0 + hy - 1, gx = gx0 + hx - 1;
        uint4 v = make_uint4(0, 0, 0, 0);
        if ((unsigned)gy < 256u && (unsigned)gx < 256u)
            v = *(const uint4*)(tbuf + ((size_t)((b << 16) + (gy << 8) + gx)) * 64 + ch * 8);
        *(uint4*)(&sm[px * 72 + ch * 8]) = v;
    }
    int oct = t & 7;
    {
        float w[8][9];
#pragma unroll
        for (int j = 0; j < 8; ++j)
#pragma unroll
            for (int k = 0; k < 9; ++k) w[j][k] = bf2f(wpe2[(oct * 8 + j) * 9 + k]);
        __syncthreads();
#pragma unroll
        for (int s = 0; s < 4; ++s) {
            int lp = (t >> 3) + s * 32;
            int ly = lp >> 5, lx = lp & 31;
            float acc[8] = {0.f, 0.f, 0.f, 0.f, 0.f, 0.f, 0.f, 0.f};
#pragma unroll
            for (int dy = 0; dy < 3; ++dy)
#pragma unroll
                for (int dx = 0; dx < 3; ++dx) {
                    int hp = (ly + dy) * 34 + lx + dx;
                    uint4 v = *(const uint4*)(&sm[hp * 72 + oct * 8]);
                    float f[8];
                    unpack8(v, f);
                    int tap = dy * 3 + dx;
#pragma unroll
                    for (int j = 0; j < 8; ++j) acc[j] += f[j] * w[j][tap];
                }
#pragma unroll
            for (int j = 0; j < 8; ++j)
                stage[lp * 68 + oct * 8 + j] = acc[j];
        }
    }
    __syncthreads();

    int lane = t & 63, wv = t >> 6;
    int col = lane & 15, quad = lane >> 4;
    const float* W = Weff + b * 4096;
    short8 bf[2][4];
#pragma unroll
    for (int kh = 0; kh < 2; ++kh)
#pragma unroll
        for (int nt = 0; nt < 4; ++nt) {
            short8 v;
#pragma unroll
            for (int j = 0; j < 8; ++j)
                v[j] = (short)f2bf(W[(kh * 32 + quad * 8 + j) * 64 + nt * 16 + col]);
            bf[kh][nt] = v;
        }
    float bias[4];
#pragma unroll
    for (int nt = 0; nt < 4; ++nt) bias[nt] = bf2f(bproj[nt * 16 + col]);

#pragma unroll
    for (int g = 0; g < 2; ++g) {
        int grp = wv * 2 + g;
        int ly = grp >> 1;
        int lxb = (grp & 1) * 16;
        size_t rowpix = (size_t)(b << 16) + ((size_t)(gy0 + ly) << 8) + gx0;
        const short8* ap = (const short8*)(xb + (rowpix + lxb + col) * 64);
        short8 a0 = ap[quad];
        short8 a1 = ap[4 + quad];
#pragma unroll
        for (int nt = 0; nt < 4; ++nt) {
            f32x4 acc = {0.f, 0.f, 0.f, 0.f};
            acc = __builtin_amdgcn_mfma_f32_16x16x32_bf16(a0, bf[0][nt], acc, 0, 0, 0);
            acc = __builtin_amdgcn_mfma_f32_16x16x32_bf16(a1, bf[1][nt], acc, 0, 0, 0);
#pragma unroll
            for (int r = 0; r < 4; ++r) {
                int lp = ly * 32 + lxb + quad * 4 + r;
                stage[lp * 68 + nt * 16 + col] += acc[r] + bias[nt];
            }
        }
    }
    __syncthreads();

#pragma unroll
    for (int k = 0; k < 8; ++k) {
        int linear = k * 256 + t;
        int px = linear >> 4, c4 = linear & 15;
        int ly = px >> 5, lx = px & 31;
        float4 v = *(const float4*)(&stage[px * 68 + c4 * 4]);
        size_t gpix = (size_t)(b << 16) + ((size_t)(gy0 + ly) << 8) + gx0 + lx;
        *(float4*)(out + gpix * 64 + c4 * 4) = v;
    }
}

// ---------------------------------------------------------------------------
extern "C" void kernel_launch(void* const* d_in, const int* in_sizes, int n_in,
                              void* d_out, int out_size, void* d_ws, size_t ws_size,
                              hipStream_t stream) {
    const float* x = (const float*)d_in[0];
    float* out = (float*)d_out;

    char* w = (char*)d_ws;
    size_t off = 0;
    auto alloc = [&](size_t bytes) -> void* {
        void* p = w + off;
        off += (bytes + 255) & ~(size_t)255;
        return p;
    };
    u16* xb = (u16*)alloc((size_t)16777216 * 2);
    u16* wb = (u16*)alloc((size_t)165128 * 2);
    u16* wqb = wb;
    u16* wkb = wqb + 32768;
    u16* wvb = wkb + 32768;
    u16* rsb = wvb + 32768;
    u16* wpb = rsb + 8;
    u16* bpb = wpb + 32768;
    u16* wcb = bpb + 64;
    u16* bcb = wcb + 32768;
    u16* p1b = bcb + 64;
    u16* p2b = p1b + 576;
    (void)wcb;

    float* partials = (float*)alloc((size_t)512 * 4096 * 4);
    float* G4       = (float*)alloc((size_t)2 * 4 * 4096 * 4);
    float* Weff     = (float*)alloc((size_t)2 * 4096 * 4);
    float* Wpos     = (float*)alloc((size_t)4096 * 4);
    u16*   pbuf     = (u16*)alloc((size_t)2 * 65536 * 64 * 2);
    u16*   tbuf     = (u16*)alloc((size_t)2 * 65536 * 64 * 2);

    hipLaunchKernelGGL(k_front, dim3(899), dim3(256), 0, stream,
                       x,
                       (const float*)d_in[1], (const float*)d_in[2], (const float*)d_in[3],
                       (const float*)d_in[4], (const float*)d_in[5], (const float*)d_in[6],
                       (const float*)d_in[7], (const float*)d_in[8], (const float*)d_in[9],
                       (const float*)d_in[10],
                       (u32*)wb, Wpos, xb, partials);
    hipLaunchKernelGGL(k_mid1, dim3(1152), dim3(256), 0, stream,
                       partials, G4, Weff, xb, Wpos, bcb, pbuf);
    hipLaunchKernelGGL(k_mid2, dim3(1040), dim3(256), 0, stream,
                       wkb, wqb, wpb, wvb, rsb, G4, Weff, pbuf, p1b, tbuf);
    hipLaunchKernelGGL(k_final, dim3(1024), dim3(256), 0, stream,
                       xb, tbuf, Weff, p2b, bpb, out);
}

// Round 4
// 155.060 us; speedup vs baseline: 1.1224x; 1.0093x over previous
//
#include <hip/hip_runtime.h>
#include <math.h>

// Dims: B=2, H=256, W=256, C=64, heads=8, dh=64, hd=512, dim_out=64.
// Inputs fp32, output fp32 (proven r1/r2). Internals bf16 + MFMA.
//
// attn[b,h,i,j] = (Wk_i^T G[b] Wq_j)/(||k_i|| ||q_j||)*rescale[h],
// G[b] = Xd^T Xd (Gram of 2x2-avg-pooled input).
// out = x@W_eff[b] + bproj + dwconv2(gelu(dwconv1(x@W_pos + bc1d)))
// W_eff[b] = Wv @ blockdiag_h(attn_h^T) @ Wproj,  W_pos = Wv @ Wc1d.
//
// R1: occupancy restructure of k_front/k_mid1.
// R2: norms/T folded into k_mid2's 16 attn blocks; 4 launches.
// R3: attn matvecs MFMA-ized with split-bf16 (hi+lo) operands.
// R4: fragment feeds fixed: transposed weight tables (wqT/wkT/wpT) written by
//     k_front -> every MFMA B/A-frag is ONE contiguous 16B load (L1-hot)
//     instead of 8 scattered 2B gathers; G pre-split to Ghi/Glo bf16 in LDS
//     (ds_read_b128 A-frags). LDS stays exactly 53248 B (conv1 3 blk/CU).

typedef unsigned short u16;
typedef unsigned int u32;
typedef __attribute__((ext_vector_type(8))) short short8;
typedef __attribute__((ext_vector_type(4))) float f32x4;

__device__ __forceinline__ float bf2f(u16 h) { return __uint_as_float(((u32)h) << 16); }
__device__ __forceinline__ u16 f2bf(float f) {
    u32 u = __float_as_uint(f);
    return (u16)((u + 0x7fffu + ((u >> 16) & 1u)) >> 16);
}
__device__ __forceinline__ float rbf(float f) { return bf2f(f2bf(f)); }
__device__ __forceinline__ u32 pk2(float lo, float hi) {
    return (u32)f2bf(lo) | ((u32)f2bf(hi) << 16);
}
__device__ __forceinline__ void unpack8(uint4 v, float* f) {
    u32 a[4] = {v.x, v.y, v.z, v.w};
#pragma unroll
    for (int i = 0; i < 4; ++i) {
        f[2 * i]     = __uint_as_float(a[i] << 16);
        f[2 * i + 1] = __uint_as_float(a[i] & 0xffff0000u);
    }
}
__device__ __forceinline__ float gelu_exact(float v) {
    return 0.5f * v * (1.f + erff(v * 0.70710678118654752f));
}
// split f32 -> bf16 hi + bf16 lo (captures ~16 mantissa bits)
__device__ __forceinline__ void splitbf(float g, short& hi, short& lo) {
    u16 hb = f2bf(g);
    hi = (short)hb;
    lo = (short)f2bf(g - bf2f(hb));
}

// ---------------------------------------------------------------------------
// K1: blocks 0..322 weight fp32->bf16 (+ transposed wqT/wkT/wpT tables);
//     323..386 Wpos = Wv@Wc1d; 387..898 pool+Gram partials + xb emit.
__global__ __launch_bounds__(256) void k_front(
    const float* __restrict__ x,
    const float* __restrict__ wq_f, const float* __restrict__ wk_f,
    const float* __restrict__ wv_f, const float* __restrict__ rs_f,
    const float* __restrict__ wp_f, const float* __restrict__ bp_f,
    const float* __restrict__ wc_f, const float* __restrict__ bc_f,
    const float* __restrict__ p1_f, const float* __restrict__ p2_f,
    u32* __restrict__ wb32, u16* __restrict__ wqT, u16* __restrict__ wkT,
    u16* __restrict__ wpT, float* __restrict__ Wpos,
    u16* __restrict__ xb, float* __restrict__ partials) {
    __shared__ float xvs[64 * 68];
    int blk = blockIdx.x;
    int t = threadIdx.x;
    if (blk < 323) {
        u32 pid = (u32)blk * 256u + t;
        if (pid < 82564u) {
            const float* src; u32 p;
            if      (pid < 16384u) { src = wq_f; p = pid; }
            else if (pid < 32768u) { src = wk_f; p = pid - 16384u; }
            else if (pid < 49152u) { src = wv_f; p = pid - 32768u; }
            else if (pid < 49156u) { src = rs_f; p = pid - 49152u; }
            else if (pid < 65540u) { src = wp_f; p = pid - 49156u; }
            else if (pid < 65572u) { src = bp_f; p = pid - 65540u; }
            else if (pid < 81956u) { src = wc_f; p = pid - 65572u; }
            else if (pid < 81988u) { src = bc_f; p = pid - 81956u; }
            else if (pid < 82276u) { src = p1_f; p = pid - 81988u; }
            else                   { src = p2_f; p = pid - 82276u; }
            wb32[pid] = (u32)f2bf(src[2 * p]) | ((u32)f2bf(src[2 * p + 1]) << 16);
            if (pid < 32768u) {               // wq / wk transposed tables
                u16* dstT = (pid < 16384u) ? wqT : wkT;
                u32 e0 = 2u * (pid & 16383u);
                u32 c = e0 >> 9, j = e0 & 511u;
                dstT[j * 64 + c]       = f2bf(src[e0]);
                dstT[(j + 1) * 64 + c] = f2bf(src[e0 + 1]);
            } else if (pid >= 49156u && pid < 65540u) {   // wp transposed
                u32 e0 = 2u * (pid - 49156u);
                u32 ip = e0 >> 6, o = e0 & 63u;
                u32 base = (ip >> 6) * 4096u + (ip & 63u);
                wpT[base + o * 64]       = f2bf(src[e0]);
                wpT[base + (o + 1) * 64] = f2bf(src[e0 + 1]);
            }
        }
    } else if (blk < 387) {
        int c = blk - 323;                    // 0..63, one Wv row per block
        int o = t & 63, ch = t >> 6;          // ch = k-chunk (one per wave)
        const float* wvr = wv_f + c * 512 + ch * 128;
        const float* wcr = wc_f + (size_t)(ch * 128) * 64 + o;
        float s = 0.f;
        for (int kk = 0; kk < 128; ++kk)
            s += rbf(wvr[kk]) * rbf(wcr[(size_t)kk * 64]);
        xvs[ch * 64 + o] = s;
        __syncthreads();
        if (t < 64)
            Wpos[c * 64 + t] = (xvs[t] + xvs[64 + t]) + (xvs[128 + t] + xvs[192 + t]);
    } else {
        int gb = blk - 387;                   // 0..511
        int b = gb >> 8, sub = gb & 255;
        int py = sub >> 1, half = sub & 1;
        const size_t rowbase = (size_t)(b * 256 + 2 * py) * 16384 + (size_t)half * 8192;
#pragma unroll
        for (int i2 = 0; i2 < 4; ++i2) {
            int u = t + 256 * i2;
            int P = u >> 4, cq = u & 15;      // P: pooled col within half (0..63)
            size_t o0 = rowbase + (size_t)(2 * P) * 64 + cq * 4;
            float4 a0 = *(const float4*)(x + o0);
            float4 a1 = *(const float4*)(x + o0 + 64);
            float4 a2 = *(const float4*)(x + o0 + 16384);
            float4 a3 = *(const float4*)(x + o0 + 16384 + 64);
            *(uint2*)(xb + o0)              = make_uint2(pk2(a0.x, a0.y), pk2(a0.z, a0.w));
            *(uint2*)(xb + o0 + 64)         = make_uint2(pk2(a1.x, a1.y), pk2(a1.z, a1.w));
            *(uint2*)(xb + o0 + 16384)      = make_uint2(pk2(a2.x, a2.y), pk2(a2.z, a2.w));
            *(uint2*)(xb + o0 + 16384 + 64) = make_uint2(pk2(a3.x, a3.y), pk2(a3.z, a3.w));
            float4 s;
            s.x = 0.25f * (a0.x + a1.x + a2.x + a3.x);
            s.y = 0.25f * (a0.y + a1.y + a2.y + a3.y);
            s.z = 0.25f * (a0.z + a1.z + a2.z + a3.z);
            s.w = 0.25f * (a0.w + a1.w + a2.w + a3.w);
            *(float4*)(&xvs[P * 68 + cq * 4]) = s;
        }
        __syncthreads();
        int r0 = (t >> 4) << 2, c0 = (t & 15) << 2;
        float acc[4][4] = {{0.f}};
        for (int P = 0; P < 64; ++P) {
            float4 av = *(const float4*)(&xvs[P * 68 + r0]);
            float4 bv = *(const float4*)(&xvs[P * 68 + c0]);
            float ar[4] = {av.x, av.y, av.z, av.w};
            float br[4] = {bv.x, bv.y, bv.z, bv.w};
#pragma unroll
            for (int i = 0; i < 4; ++i)
#pragma unroll
                for (int j = 0; j < 4; ++j)
                    acc[i][j] += ar[i] * br[j];
        }
        float* outp = partials + (size_t)gb * 4096;
#pragma unroll
        for (int i = 0; i < 4; ++i)
            *(float4*)(&outp[(r0 + i) * 64 + c0]) =
                make_float4(acc[i][0], acc[i][1], acc[i][2], acc[i][3]);
    }
}

// ---------------------------------------------------------------------------
// K2: blocks 0..127 Gram reduce into 4-chunk G4 (+Weff zero);
//     128..1151 pmain (MFMA matvec, 128 px per block).
__global__ __launch_bounds__(256) void k_mid1(
    const float* __restrict__ partials, float* __restrict__ G4, float* __restrict__ Weff,
    const u16* __restrict__ xb, const float* __restrict__ Wpos,
    const u16* __restrict__ bc1d, u16* __restrict__ pbuf) {
    __shared__ u16 sm[128 * 72];
    int blk = blockIdx.x;
    int t = threadIdx.x;
    if (blk < 128) {
        int gid = blk * 256 + t;              // 0..32767
        int e = gid & 4095, ch = (gid >> 12) & 3, b = gid >> 14;
        const float* p0 = partials + ((size_t)(b * 256 + ch * 64)) * 4096 + e;
        float s = 0.f;
        for (int p = 0; p < 64; ++p)
            s += p0[(size_t)p * 4096];
        G4[gid] = s;
        if (gid < 8192) Weff[gid] = 0.f;
        return;
    }
    int pb = blk - 128;                       // 0..1023
    int lane = t & 63, wv = t >> 6;
    int col = lane & 15, quad = lane >> 4;

    short8 bf[2][4];
#pragma unroll
    for (int kh = 0; kh < 2; ++kh)
#pragma unroll
        for (int nt = 0; nt < 4; ++nt) {
            short8 v;
#pragma unroll
            for (int j = 0; j < 8; ++j)
                v[j] = (short)f2bf(Wpos[(kh * 32 + quad * 8 + j) * 64 + nt * 16 + col]);
            bf[kh][nt] = v;
        }
    float bias[4];
#pragma unroll
    for (int nt = 0; nt < 4; ++nt) bias[nt] = bf2f(bc1d[nt * 16 + col]);

    size_t base = (size_t)pb * 128;
#pragma unroll
    for (int g = 0; g < 2; ++g) {
        int P0 = wv * 32 + g * 16;
        const short8* ap = (const short8*)(xb + (base + P0 + col) * 64);
        short8 a0 = ap[quad];
        short8 a1 = ap[4 + quad];
#pragma unroll
        for (int nt = 0; nt < 4; ++nt) {
            f32x4 acc = {0.f, 0.f, 0.f, 0.f};
            acc = __builtin_amdgcn_mfma_f32_16x16x32_bf16(a0, bf[0][nt], acc, 0, 0, 0);
            acc = __builtin_amdgcn_mfma_f32_16x16x32_bf16(a1, bf[1][nt], acc, 0, 0, 0);
#pragma unroll
            for (int r = 0; r < 4; ++r)
                sm[(P0 + quad * 4 + r) * 72 + nt * 16 + col] = f2bf(acc[r] + bias[nt]);
        }
    }
    __syncthreads();
#pragma unroll
    for (int k = 0; k < 4; ++k) {
        int linear = k * 256 + t;
        int px = linear >> 3, oct = linear & 7;
        uint4 v = *(const uint4*)(&sm[px * 72 + oct * 8]);
        *(uint4*)(pbuf + (base + px) * 64 + oct * 8) = v;
    }
}

// ---------------------------------------------------------------------------
// K3: blocks 0..15 self-sufficient attn (MFMA, frag-friendly feeds);
//     16..1039 conv1.
// Attn LDS (53248 B exactly):
//   [0..18432)      Ghi[64][72]u16 @0, Glo @9216; after phase 1 ->
//                   Lraw/attn f32[64][68] (17408).
//   [18432..35840)  TkS f32[64][68]; pads col64=nk, col65=nq; after phase 2b
//                   -> P f32[64][68] (cols 0..63).
//   [35840..53248)  TqS f32[64][68]; pads col64..67 = norm partials.
__global__ __launch_bounds__(256) void k_mid2(
    const u16* __restrict__ wqT, const u16* __restrict__ wkT,
    const u16* __restrict__ wpT, const u16* __restrict__ wvb,
    const u16* __restrict__ rsb,
    const float* __restrict__ G4, float* __restrict__ Weff,
    const u16* __restrict__ pbuf, const u16* __restrict__ wpe1, u16* __restrict__ tbuf) {
    __shared__ __align__(16) char shm[53248];
    int blk = blockIdx.x, t = threadIdx.x;
    if (blk < 16) {
        u16*   GhiL = (u16*)shm;
        u16*   GloL = (u16*)(shm + 9216);
        float* Lraw = (float*)shm;
        float* TkS  = (float*)(shm + 18432);
        float* TqS  = (float*)(shm + 35840);
        int b = blk >> 3, h = blk & 7;
        int lane = t & 63, w = t >> 6;        // w = wave = m-band (16 rows)
        int lr = lane & 15, lq = lane >> 4;
        {   // phase 0: G = sum of 4 G4 chunks; split -> Ghi/Glo (row-major)
            int base = t * 16;
            int row = base >> 6, col = base & 63;
            const float* Gb = G4 + (size_t)b * 16384;
#pragma unroll
            for (int half = 0; half < 2; ++half) {
                short8 hi8, lo8;
#pragma unroll
                for (int q = 0; q < 8; ++q) {
                    int e = base + half * 8 + q;
                    float g = (Gb[e] + Gb[4096 + e]) + (Gb[8192 + e] + Gb[12288 + e]);
                    short hh, ll; splitbf(g, hh, ll);
                    hi8[q] = hh; lo8[q] = ll;
                }
                *(short8*)(&GhiL[row * 72 + col + half * 8]) = hi8;
                *(short8*)(&GloL[row * 72 + col + half * 8]) = lo8;
            }
        }
        __syncthreads();
        {   // phase 1: Tk = G@Wk_h -> TkS ; Tq = G@Wq_h -> TqS.
            // A-frag: G row-major (symmetric => G[m][k] ok), b128 LDS reads.
            // B-frag: one short8 global load from transposed table (L1-hot).
            short8 ahi[2], alo[2];
#pragma unroll
            for (int ks = 0; ks < 2; ++ks) {
                ahi[ks] = *(const short8*)(&GhiL[(w * 16 + lr) * 72 + ks * 32 + lq * 8]);
                alo[ks] = *(const short8*)(&GloL[(w * 16 + lr) * 72 + ks * 32 + lq * 8]);
            }
#pragma unroll
            for (int sel = 0; sel < 2; ++sel) {
                const u16* WT = sel ? wqT : wkT;
                float* outp = sel ? TqS : TkS;
#pragma unroll
                for (int nt = 0; nt < 4; ++nt) {
                    f32x4 acc = {0.f, 0.f, 0.f, 0.f};
#pragma unroll
                    for (int ks = 0; ks < 2; ++ks) {
                        short8 bv = *(const short8*)(&WT[(h * 64 + nt * 16 + lr) * 64 + ks * 32 + lq * 8]);
                        acc = __builtin_amdgcn_mfma_f32_16x16x32_bf16(ahi[ks], bv, acc, 0, 0, 0);
                        acc = __builtin_amdgcn_mfma_f32_16x16x32_bf16(alo[ks], bv, acc, 0, 0, 0);
                    }
#pragma unroll
                    for (int r = 0; r < 4; ++r)
                        outp[(w * 16 + lq * 4 + r) * 68 + nt * 16 + lr] = acc[r];
                }
            }
        }
        __syncthreads();
        {   // phase 2a: nk partials (Wk .* Tk) -> TqS pads
            int ci = t & 63, grp = t >> 6;
            const u16* wr = wkT + (h * 64 + ci) * 64 + grp * 16;
            float s = 0.f;
#pragma unroll
            for (int cc = 0; cc < 16; ++cc)
                s += bf2f(wr[cc]) * TkS[(grp * 16 + cc) * 68 + ci];
            TqS[ci * 68 + 64 + grp] = s;
        }
        __syncthreads();
        // phase 2b: nk combine -> TkS pad; Lraw = Wk^T @ Tq -> region0
        if (t < 64) {
            float s = (TqS[t * 68 + 64] + TqS[t * 68 + 65]) +
                      (TqS[t * 68 + 66] + TqS[t * 68 + 67]);
            TkS[t * 68 + 64] = fmaxf(sqrtf(fmaxf(s, 0.f)), 1e-12f);   // nk
        }
        {
            short8 ak[2];
#pragma unroll
            for (int ks = 0; ks < 2; ++ks)
                ak[ks] = *(const short8*)(&wkT[(h * 64 + w * 16 + lr) * 64 + ks * 32 + lq * 8]);
#pragma unroll
            for (int nt = 0; nt < 4; ++nt) {
                f32x4 acc = {0.f, 0.f, 0.f, 0.f};
#pragma unroll
                for (int ks = 0; ks < 2; ++ks) {
                    short8 bhi, blo;
#pragma unroll
                    for (int jj = 0; jj < 8; ++jj) {
                        short h16, l16;
                        splitbf(TqS[(ks * 32 + lq * 8 + jj) * 68 + nt * 16 + lr], h16, l16);
                        bhi[jj] = h16; blo[jj] = l16;
                    }
                    acc = __builtin_amdgcn_mfma_f32_16x16x32_bf16(ak[ks], bhi, acc, 0, 0, 0);
                    acc = __builtin_amdgcn_mfma_f32_16x16x32_bf16(ak[ks], blo, acc, 0, 0, 0);
                }
#pragma unroll
                for (int r = 0; r < 4; ++r)
                    Lraw[(w * 16 + lq * 4 + r) * 68 + nt * 16 + lr] = acc[r];
            }
        }
        __syncthreads();
        {   // phase 2c: nq partials (Wq .* Tq) -> TqS pads (nk already combined)
            int ci = t & 63, grp = t >> 6;
            const u16* wr = wqT + (h * 64 + ci) * 64 + grp * 16;
            float s = 0.f;
#pragma unroll
            for (int cc = 0; cc < 16; ++cc)
                s += bf2f(wr[cc]) * TqS[(grp * 16 + cc) * 68 + ci];
            TqS[ci * 68 + 64 + grp] = s;
        }
        __syncthreads();
        // phase 2d: nq combine
        if (t < 64) {
            float s = (TqS[t * 68 + 64] + TqS[t * 68 + 65]) +
                      (TqS[t * 68 + 66] + TqS[t * 68 + 67]);
            TkS[t * 68 + 65] = fmaxf(sqrtf(fmaxf(s, 0.f)), 1e-12f);   // nq
        }
        __syncthreads();
        {   // phase 3: scale + softmax (Lraw) -> attn in place
            int i = t >> 2, jq = t & 3, j0 = jq * 16;
            float L[16];
#pragma unroll
            for (int q = 0; q < 4; ++q) {
                float4 lv = *(const float4*)(&Lraw[i * 68 + j0 + 4 * q]);
                L[4 * q] = lv.x; L[4 * q + 1] = lv.y;
                L[4 * q + 2] = lv.z; L[4 * q + 3] = lv.w;
            }
            float rs = bf2f(rsb[h]);
            float nki = TkS[i * 68 + 64];
            float nqv[16];
#pragma unroll
            for (int jj = 0; jj < 16; ++jj) nqv[jj] = TkS[(j0 + jj) * 68 + 65];
            float m = -1e30f;
#pragma unroll
            for (int jj = 0; jj < 16; ++jj) {
                L[jj] = L[jj] * rs / (nki * nqv[jj]);
                m = fmaxf(m, L[jj]);
            }
            m = fmaxf(m, __shfl_xor(m, 1));
            m = fmaxf(m, __shfl_xor(m, 2));
            float s = 0.f;
#pragma unroll
            for (int jj = 0; jj < 16; ++jj) {
                L[jj] = __expf(L[jj] - m);
                s += L[jj];
            }
            s += __shfl_xor(s, 1);
            s += __shfl_xor(s, 2);
            float inv = 1.f / s;
#pragma unroll
            for (int q = 0; q < 4; ++q)
                *(float4*)(&Lraw[i * 68 + j0 + 4 * q]) =
                    make_float4(L[4 * q] * inv, L[4 * q + 1] * inv,
                                L[4 * q + 2] * inv, L[4 * q + 3] * inv);
        }
        __syncthreads();
        {   // phase 4: P = attn^T @ Wproj_h -> TkS region (cols 0..63)
            short8 ahi[2], alo[2];
#pragma unroll
            for (int ks = 0; ks < 2; ++ks) {
                short8 hi, lo;
#pragma unroll
                for (int jj = 0; jj < 8; ++jj) {
                    short h16, l16;
                    splitbf(Lraw[(ks * 32 + lq * 8 + jj) * 68 + w * 16 + lr], h16, l16);
                    hi[jj] = h16; lo[jj] = l16;
                }
                ahi[ks] = hi; alo[ks] = lo;
            }
#pragma unroll
            for (int nt = 0; nt < 4; ++nt) {
                f32x4 acc = {0.f, 0.f, 0.f, 0.f};
#pragma unroll
                for (int ks = 0; ks < 2; ++ks) {
                    short8 bv = *(const short8*)(&wpT[h * 4096 + (nt * 16 + lr) * 64 + ks * 32 + lq * 8]);
                    acc = __builtin_amdgcn_mfma_f32_16x16x32_bf16(ahi[ks], bv, acc, 0, 0, 0);
                    acc = __builtin_amdgcn_mfma_f32_16x16x32_bf16(alo[ks], bv, acc, 0, 0, 0);
                }
#pragma unroll
                for (int r = 0; r < 4; ++r)
                    TkS[(w * 16 + lq * 4 + r) * 68 + nt * 16 + lr] = acc[r];
            }
        }
        __syncthreads();
        {   // phase 5: Weff += Wv_h @ P -> atomicAdd
            short8 av[2];
#pragma unroll
            for (int ks = 0; ks < 2; ++ks)
                av[ks] = *(const short8*)(&wvb[(w * 16 + lr) * 512 + h * 64 + ks * 32 + lq * 8]);
            float* W = Weff + b * 4096;
#pragma unroll
            for (int nt = 0; nt < 4; ++nt) {
                f32x4 acc = {0.f, 0.f, 0.f, 0.f};
#pragma unroll
                for (int ks = 0; ks < 2; ++ks) {
                    short8 bhi, blo;
#pragma unroll
                    for (int jj = 0; jj < 8; ++jj) {
                        short h16, l16;
                        splitbf(TkS[(ks * 32 + lq * 8 + jj) * 68 + nt * 16 + lr], h16, l16);
                        bhi[jj] = h16; blo[jj] = l16;
                    }
                    acc = __builtin_amdgcn_mfma_f32_16x16x32_bf16(av[ks], bhi, acc, 0, 0, 0);
                    acc = __builtin_amdgcn_mfma_f32_16x16x32_bf16(av[ks], blo, acc, 0, 0, 0);
                }
#pragma unroll
                for (int r = 0; r < 4; ++r)
                    atomicAdd(&W[(w * 16 + lq * 4 + r) * 64 + nt * 16 + lr], acc[r]);
            }
        }
        return;
    }
    // ---- conv1 (proven round-4 body), cb = blk - 16 ----
    u16* sm = (u16*)shm;                       // 204*72 u16 = 29376 B
    int cb = blk - 16;
    int b  = cb >> 9;
    int ty = (cb >> 3) & 63;
    int tx = cb & 7;
    int gy0 = ty * 4, gx0 = tx * 32;

    for (int i = t; i < 1632; i += 256) {
        int px = i >> 3, ch = i & 7;
        int hy = px / 34, hx = px - hy * 34;
        int gy = gy0 + hy - 1, gx = gx0 + hx - 1;
        uint4 v = make_uint4(0, 0, 0, 0);
        if ((unsigned)gy < 256u && (unsigned)gx < 256u)
            v = *(const uint4*)(pbuf + ((size_t)((b << 16) + (gy << 8) + gx)) * 64 + ch * 8);
        *(uint4*)(&sm[px * 72 + ch * 8]) = v;
    }
    int oct = t & 7;
    float w[8][9];
#pragma unroll
    for (int j = 0; j < 8; ++j)
#pragma unroll
        for (int k = 0; k < 9; ++k) w[j][k] = bf2f(wpe1[(oct * 8 + j) * 9 + k]);
    __syncthreads();

#pragma unroll
    for (int s = 0; s < 4; ++s) {
        int lp = (t >> 3) + s * 32;
        int ly = lp >> 5, lx = lp & 31;
        float acc[8] = {0.f, 0.f, 0.f, 0.f, 0.f, 0.f, 0.f, 0.f};
#pragma unroll
        for (int dy = 0; dy < 3; ++dy)
#pragma unroll
            for (int dx = 0; dx < 3; ++dx) {
                int hp = (ly + dy) * 34 + lx + dx;
                uint4 v = *(const uint4*)(&sm[hp * 72 + oct * 8]);
                float f[8];
                unpack8(v, f);
                int tap = dy * 3 + dx;
#pragma unroll
                for (int j = 0; j < 8; ++j) acc[j] += f[j] * w[j][tap];
            }
        u32 pk[4];
#pragma unroll
        for (int q = 0; q < 4; ++q)
            pk[q] = pk2(gelu_exact(acc[2 * q]), gelu_exact(acc[2 * q + 1]));
        size_t gpix = (size_t)(b << 16) + ((size_t)(gy0 + ly) << 8) + gx0 + lx;
        *(uint4*)(tbuf + gpix * 64 + oct * 8) = make_uint4(pk[0], pk[1], pk[2], pk[3]);
    }
}

// ---------------------------------------------------------------------------
// K4: out = xb @ Weff[b] + bproj + dwconv3x3(tbuf, Wpe2) (proven round-4 body)
__global__ __launch_bounds__(256) void k_final(const u16* __restrict__ xb,
                                               const u16* __restrict__ tbuf,
                                               const float* __restrict__ Weff,
                                               const u16* __restrict__ wpe2,
                                               const u16* __restrict__ bproj,
                                               float* __restrict__ out) {
    __shared__ u16 sm[204 * 72];
    __shared__ float stage[128 * 68];
    int t = threadIdx.x;
    int blk = blockIdx.x;
    int b  = blk >> 9;
    int ty = (blk >> 3) & 63;
    int tx = blk & 7;
    int gy0 = ty * 4, gx0 = tx * 32;

    for (int i = t; i < 1632; i += 256) {
        int px = i >> 3, ch = i & 7;
        int hy = px / 34, hx = px - hy * 34;
        int gy = gy0 + hy - 1, gx = gx0 + hx - 1;
        uint4 v = make_uint4(0, 0, 0, 0);
        if ((unsigned)gy < 256u && (unsigned)gx < 256u)
            v = *(const uint4*)(tbuf + ((size_t)((b << 16) + (gy << 8) + gx)) * 64 + ch * 8);
        *(uint4*)(&sm[px * 72 + ch * 8]) = v;
    }
    int oct = t & 7;
    {
        float w[8][9];
#pragma unroll
        for (int j = 0; j < 8; ++j)
#pragma unroll
            for (int k = 0; k < 9; ++k) w[j][k] = bf2f(wpe2[(oct * 8 + j) * 9 + k]);
        __syncthreads();
#pragma unroll
        for (int s = 0; s < 4; ++s) {
            int lp = (t >> 3) + s * 32;
            int ly = lp >> 5, lx = lp & 31;
            float acc[8] = {0.f, 0.f, 0.f, 0.f, 0.f, 0.f, 0.f, 0.f};
#pragma unroll
            for (int dy = 0; dy < 3; ++dy)
#pragma unroll
                for (int dx = 0; dx < 3; ++dx) {
                    int hp = (ly + dy) * 34 + lx + dx;
                    uint4 v = *(const uint4*)(&sm[hp * 72 + oct * 8]);
                    float f[8];
                    unpack8(v, f);
                    int tap = dy * 3 + dx;
#pragma unroll
                    for (int j = 0; j < 8; ++j) acc[j] += f[j] * w[j][tap];
                }
#pragma unroll
            for (int j = 0; j < 8; ++j)
                stage[lp * 68 + oct * 8 + j] = acc[j];
        }
    }
    __syncthreads();

    int lane = t & 63, wv = t >> 6;
    int col = lane & 15, quad = lane >> 4;
    const float* W = Weff + b * 4096;
    short8 bf[2][4];
#pragma unroll
    for (int kh = 0; kh < 2; ++kh)
#pragma unroll
        for (int nt = 0; nt < 4; ++nt) {
            short8 v;
#pragma unroll
            for (int j = 0; j < 8; ++j)
                v[j] = (short)f2bf(W[(kh * 32 + quad * 8 + j) * 64 + nt * 16 + col]);
            bf[kh][nt] = v;
        }
    float bias[4];
#pragma unroll
    for (int nt = 0; nt < 4; ++nt) bias[nt] = bf2f(bproj[nt * 16 + col]);

#pragma unroll
    for (int g = 0; g < 2; ++g) {
        int grp = wv * 2 + g;
        int ly = grp >> 1;
        int lxb = (grp & 1) * 16;
        size_t rowpix = (size_t)(b << 16) + ((size_t)(gy0 + ly) << 8) + gx0;
        const short8* ap = (const short8*)(xb + (rowpix + lxb + col) * 64);
        short8 a0 = ap[quad];
        short8 a1 = ap[4 + quad];
#pragma unroll
        for (int nt = 0; nt < 4; ++nt) {
            f32x4 acc = {0.f, 0.f, 0.f, 0.f};
            acc = __builtin_amdgcn_mfma_f32_16x16x32_bf16(a0, bf[0][nt], acc, 0, 0, 0);
            acc = __builtin_amdgcn_mfma_f32_16x16x32_bf16(a1, bf[1][nt], acc, 0, 0, 0);
#pragma unroll
            for (int r = 0; r < 4; ++r) {
                int lp = ly * 32 + lxb + quad * 4 + r;
                stage[lp * 68 + nt * 16 + col] += acc[r] + bias[nt];
            }
        }
    }
    __syncthreads();

#pragma unroll
    for (int k = 0; k < 8; ++k) {
        int linear = k * 256 + t;
        int px = linear >> 4, c4 = linear & 15;
        int ly = px >> 5, lx = px & 31;
        float4 v = *(const float4*)(&stage[px * 68 + c4 * 4]);
        size_t gpix = (size_t)(b << 16) + ((size_t)(gy0 + ly) << 8) + gx0 + lx;
        *(float4*)(out + gpix * 64 + c4 * 4) = v;
    }
}

// ---------------------------------------------------------------------------
extern "C" void kernel_launch(void* const* d_in, const int* in_sizes, int n_in,
                              void* d_out, int out_size, void* d_ws, size_t ws_size,
                              hipStream_t stream) {
    const float* x = (const float*)d_in[0];
    float* out = (float*)d_out;

    char* w = (char*)d_ws;
    size_t off = 0;
    auto alloc = [&](size_t bytes) -> void* {
        void* p = w + off;
        off += (bytes + 255) & ~(size_t)255;
        return p;
    };
    u16* xb = (u16*)alloc((size_t)16777216 * 2);
    u16* wb = (u16*)alloc((size_t)165128 * 2);
    u16* wqb = wb;
    u16* wkb = wqb + 32768;
    u16* wvb = wkb + 32768;
    u16* rsb = wvb + 32768;
    u16* wpb = rsb + 8;
    u16* bpb = wpb + 32768;
    u16* wcb = bpb + 64;
    u16* bcb = wcb + 32768;
    u16* p1b = bcb + 64;
    u16* p2b = p1b + 576;
    (void)wcb; (void)wqb; (void)wkb; (void)wpb;

    u16* wqT = (u16*)alloc((size_t)32768 * 2);
    u16* wkT = (u16*)alloc((size_t)32768 * 2);
    u16* wpT = (u16*)alloc((size_t)32768 * 2);

    float* partials = (float*)alloc((size_t)512 * 4096 * 4);
    float* G4       = (float*)alloc((size_t)2 * 4 * 4096 * 4);
    float* Weff     = (float*)alloc((size_t)2 * 4096 * 4);
    float* Wpos     = (float*)alloc((size_t)4096 * 4);
    u16*   pbuf     = (u16*)alloc((size_t)2 * 65536 * 64 * 2);
    u16*   tbuf     = (u16*)alloc((size_t)2 * 65536 * 64 * 2);

    hipLaunchKernelGGL(k_front, dim3(899), dim3(256), 0, stream,
                       x,
                       (const float*)d_in[1], (const float*)d_in[2], (const float*)d_in[3],
                       (const float*)d_in[4], (const float*)d_in[5], (const float*)d_in[6],
                       (const float*)d_in[7], (const float*)d_in[8], (const float*)d_in[9],
                       (const float*)d_in[10],
                       (u32*)wb, wqT, wkT, wpT, Wpos, xb, partials);
    hipLaunchKernelGGL(k_mid1, dim3(1152), dim3(256), 0, stream,
                       partials, G4, Weff, xb, Wpos, bcb, pbuf);
    hipLaunchKernelGGL(k_mid2, dim3(1040), dim3(256), 0, stream,
                       wqT, wkT, wpT, wvb, rsb, G4, Weff, pbuf, p1b, tbuf);
    hipLaunchKernelGGL(k_final, dim3(1024), dim3(256), 0, stream,
                       xb, tbuf, Weff, p2b, bpb, out);
}